// Round 18
// baseline (316.039 us; speedup 1.0000x reference)
//
#include <hip/hip_runtime.h>
#include <hip/hip_bf16.h>
#include <hip/hip_fp8.h>
#include <math.h>

#define N 4096
#define D 1024
#define NINST 8
#define NGROUP (N / NINST)
#define ALPHA 20.0f
#define MARGIN 0.5f
#define NB 64            // 64-row bands
#define NTILE (NB * (NB + 1) / 2)   // 2080 triangular tiles
#define NBLK 512

typedef __attribute__((ext_vector_type(4))) float f32x4;

__device__ __forceinline__ unsigned fkey(float f) {
    int b = __float_as_int(f);
    return (b >= 0) ? ((unsigned)b | 0x80000000u) : ~(unsigned)b;
}
__device__ __forceinline__ float fdec(unsigned u) {
    int b = (u & 0x80000000u) ? (int)(u ^ 0x80000000u) : ~(int)u;
    return __int_as_float(b);
}

__device__ __forceinline__ float softplus(float x) {
    float z = __expf(-fabsf(x));
    return fmaxf(x, 0.0f) + __logf(1.0f + z);
}

__device__ __forceinline__ void gld16(const void* g, void* l) {
    __builtin_amdgcn_global_load_lds(
        (const __attribute__((address_space(1))) void*)g,
        (__attribute__((address_space(3))) void*)l, 16, 0, 0);
}

// ---------------- fused kernel: normalize+Gram -> sim tiles -> row combine ----------------
// grid 512 x 256 (4 waves). ctrl: [0]=gmax [1]=sem2 [2]=cnt3 [4..67]=band_cnt[64].
// Sync discipline (R13 lesson): spins use RELAXED loads (no cache inv) + s_sleep;
// exactly ONE release fence before each counter add, ONE acquire after each spin.
// Deadlock-free: every block publishes its group BEFORE any spin; all 512 blocks
// co-resident (49.6KB LDS -> >=2 blocks/CU; 512 <= capacity).
__global__ __launch_bounds__(256, 2) void k_all(const float* __restrict__ in,
                                                unsigned long* __restrict__ xn8,
                                                float* __restrict__ pos_sims,
                                                float* __restrict__ min_pos,
                                                float* __restrict__ sum_part,
                                                int* __restrict__ cnt_part,
                                                float* __restrict__ max_part,
                                                unsigned* __restrict__ ctrl,
                                                float* __restrict__ accum,
                                                float* __restrict__ out) {
    __shared__ __align__(16) char smem[49152];   // phase1: srows4 (32.9KB) / phase2: 4x12KB rings
    __shared__ float spart[8][4];
    __shared__ float sinv[8];
    __shared__ float sg[8][8];
    __shared__ float sloss[8];

    unsigned* gmax     = ctrl + 0;
    unsigned* sem2     = ctrl + 1;
    unsigned* cnt3     = ctrl + 2;
    unsigned* band_cnt = ctrl + 4;

    int bid = blockIdx.x;
    int t = threadIdx.x;
    int w = t >> 6;
    int l = t & 63;

    // ===================== PHASE 1: group bid -> fp8 fragment-major + Gram =====================
    {
        int g = bid;
        int lane = l, wid = w;
        float4* srows4 = (float4*)smem;   // [8][257]

        const float4* in4 = (const float4*)in;
        #pragma unroll
        for (int i = 0; i < 8; ++i) {
            float4 v = in4[(size_t)g * 2048 + i * 256 + t];
            srows4[i * 257 + t] = v;
            float ss = v.x * v.x + v.y * v.y + v.z * v.z + v.w * v.w;
            #pragma unroll
            for (int off = 1; off < 64; off <<= 1) ss += __shfl_xor(ss, off);
            if (lane == 0) spart[i][wid] = ss;
        }
        __syncthreads();
        if (t < 8) sinv[t] = rsqrtf(spart[t][0] + spart[t][1] + spart[t][2] + spart[t][3]);
        __syncthreads();

        // fragment-major fp8 write: 4 ulong slots per thread
        {
            int i_row = t & 7;
            int oct  = (t >> 3) & 3;
            int k0b  = t >> 5;
            size_t base = (size_t)(g >> 3) * 8192 + (size_t)((g >> 1) & 3) * 64
                        + (size_t)(oct * 16 + (g & 1) * 8 + i_row);
            float inv = sinv[i_row];
            #pragma unroll
            for (int j = 0; j < 4; ++j) {
                int k0 = k0b + j * 8;
                float4 v0 = srows4[i_row * 257 + k0 * 8 + oct * 2];
                float4 v1 = srows4[i_row * 257 + k0 * 8 + oct * 2 + 1];
                union { unsigned char c[8]; unsigned long u64; } o;
                o.c[0] = __hip_fp8_e4m3(v0.x * inv).__x;
                o.c[1] = __hip_fp8_e4m3(v0.y * inv).__x;
                o.c[2] = __hip_fp8_e4m3(v0.z * inv).__x;
                o.c[3] = __hip_fp8_e4m3(v0.w * inv).__x;
                o.c[4] = __hip_fp8_e4m3(v1.x * inv).__x;
                o.c[5] = __hip_fp8_e4m3(v1.y * inv).__x;
                o.c[6] = __hip_fp8_e4m3(v1.z * inv).__x;
                o.c[7] = __hip_fp8_e4m3(v1.w * inv).__x;
                xn8[base + (size_t)k0 * 256] = o.u64;
            }
        }

        // Gram: staggered start (bank-uniform)
        int pair = t >> 2, a = pair >> 3, b = pair & 7, slice = t & 3;
        const float4* pa = srows4 + a * 257 + slice * 64;
        const float4* pb = srows4 + b * 257 + slice * 64;
        int j0 = (pair + slice * 2) & 63;
        float s = 0.f;
        #pragma unroll 8
        for (int i = 0; i < 64; ++i) {
            int j = (i + j0) & 63;
            float4 x = pa[j], y = pb[j];
            s += x.x * y.x + x.y * y.y + x.z * y.z + x.w * y.w;
        }
        s += __shfl_xor(s, 1);
        s += __shfl_xor(s, 2);
        if (slice == 0) sg[a][b] = s * sinv[a] * sinv[b];
        __syncthreads();
        if (t < 8) {
            float mn = 1e30f;
            int idx = 0;
            #pragma unroll
            for (int b2 = 0; b2 < 8; ++b2) {
                if (b2 == t) continue;
                float v = sg[t][b2];
                mn = fminf(mn, v);
                pos_sims[(size_t)(g * 8 + t) * 8 + idx] = v;
                ++idx;
            }
            min_pos[g * 8 + t] = mn;
        }
        __syncthreads();
        __threadfence();   // release this block's xn8/min_pos/pos_sims
        if (t == 0)
            __hip_atomic_fetch_add(&band_cnt[bid >> 3], 1u,
                                   __ATOMIC_RELAXED, __HIP_MEMORY_SCOPE_AGENT);
    }
    __syncthreads();   // smem (srows4) free -> rings

    // ===================== PHASE 2: fp8 MFMA sim tiles (per-wave, band-gated) =====================
    {
        int lrow = l & 15;
        int kgrp = l >> 4;
        char* ring = smem + w * 12288;   // 3 stages x 4KB per wave

        for (int u = bid * 4 + w; u < NTILE; u += 4 * NBLK) {
            int rt = 0, rem = u;
            while (rem >= NB - rt) { rem -= NB - rt; ++rt; }
            int ct = rt + rem;
            bool diag = (rt == ct);
            int R0 = rt * 64, C0 = ct * 64;

            // wait for both bands (relaxed polls; one acquire after)
            if (l == 0) {
                while (__hip_atomic_load(&band_cnt[rt], __ATOMIC_RELAXED,
                                         __HIP_MEMORY_SCOPE_AGENT) < 8u ||
                       __hip_atomic_load(&band_cnt[ct], __ATOMIC_RELAXED,
                                         __HIP_MEMORY_SCOPE_AGENT) < 8u)
                    __builtin_amdgcn_s_sleep(8);
            }
            __threadfence();   // acquire: invalidate stale lines before reading bands

            float mA = min_pos[R0 + l];
            float mB = min_pos[C0 + l];
            asm volatile("s_waitcnt vmcnt(0)" ::: "memory");   // exact vmcnt bookkeeping

            const char* xb = (const char*)xn8;
            const char* gA = xb + (size_t)rt * 65536 + (size_t)l * 16;
            const char* gB = xb + (size_t)ct * 65536 + (size_t)l * 16;

            #define STAGE(s_)                                                   \
                do {                                                            \
                    char* d_ = ring + ((s_) % 3) * 4096;                        \
                    gld16(gA + (size_t)(s_) * 2048,        d_);                 \
                    gld16(gA + (size_t)(s_) * 2048 + 1024, d_ + 1024);          \
                    gld16(gB + (size_t)(s_) * 2048,        d_ + 2048);          \
                    gld16(gB + (size_t)(s_) * 2048 + 1024, d_ + 3072);          \
                } while (0)

            STAGE(0); STAGE(1); STAGE(2);

            f32x4 zero = {0.f, 0.f, 0.f, 0.f};
            f32x4 acc[4][4];
            #pragma unroll
            for (int m = 0; m < 4; ++m)
                #pragma unroll
                for (int n = 0; n < 4; ++n) acc[m][n] = zero;

            for (int it = 0; it < 32; ++it) {
                if (it <= 29)      asm volatile("s_waitcnt vmcnt(8)" ::: "memory");
                else if (it == 30) asm volatile("s_waitcnt vmcnt(4)" ::: "memory");
                else               asm volatile("s_waitcnt vmcnt(0)" ::: "memory");

                const char* buf = ring + (it % 3) * 4096;
                long a[4], b[4];
                #pragma unroll
                for (int m = 0; m < 4; ++m) {
                    a[m] = *(const long*)(buf + m * 512 + l * 8);
                    b[m] = *(const long*)(buf + 2048 + m * 512 + l * 8);
                }

                #pragma unroll
                for (int m = 0; m < 4; ++m)
                    #pragma unroll
                    for (int n = 0; n < 4; ++n)
                        acc[m][n] = __builtin_amdgcn_mfma_f32_16x16x32_fp8_fp8(
                            a[m], b[n], acc[m][n], 0, 0, 0);

                asm volatile("s_waitcnt lgkmcnt(0)" ::: "memory");
                if (it <= 28) STAGE(it + 3);
            }
            #undef STAGE

            // epilogue: row-band stats; col-band (transpose) stats for off-diag
            float allmax = -1e30f;
            float thB[4];
            #pragma unroll
            for (int n = 0; n < 4; ++n) thB[n] = __shfl(mB, n * 16 + lrow) - 0.05f;

            float colS[4] = {0.f, 0.f, 0.f, 0.f};
            float colM[4] = {-1e30f, -1e30f, -1e30f, -1e30f};
            int   colC[4] = {0, 0, 0, 0};

            #pragma unroll
            for (int m = 0; m < 4; ++m) {
                #pragma unroll
                for (int reg = 0; reg < 4; ++reg) {
                    int lr = m * 16 + kgrp * 4 + reg;
                    int grow = R0 + lr;
                    float th = __shfl(mA, lr) - 0.05f;
                    int gi = grow >> 3;
                    float rs = 0.f, rm = -1e30f;
                    int rc = 0;
                    #pragma unroll
                    for (int n = 0; n < 4; ++n) {
                        int gcol = C0 + n * 16 + lrow;
                        float s = acc[m][n][reg];
                        allmax = fmaxf(allmax, s);
                        if ((gcol >> 3) != gi) {
                            float e = softplus(ALPHA * (s - MARGIN));
                            rm = fmaxf(rm, s);
                            if (s > th) { rs += e; rc += 1; }
                            if (!diag) {
                                colM[n] = fmaxf(colM[n], s);
                                if (s > thB[n]) { colS[n] += e; colC[n] += 1; }
                            }
                        }
                    }
                    #pragma unroll
                    for (int off = 1; off < 16; off <<= 1) {
                        rs += __shfl_xor(rs, off);
                        rc += __shfl_xor(rc, off);
                        rm = fmaxf(rm, __shfl_xor(rm, off));
                    }
                    if (lrow == 0) {
                        sum_part[(size_t)grow * 64 + ct] = rs;
                        cnt_part[(size_t)grow * 64 + ct] = rc;
                        max_part[(size_t)grow * 64 + ct] = rm;
                    }
                }
            }

            if (!diag) {
                #pragma unroll
                for (int n = 0; n < 4; ++n) {
                    float cs = colS[n], cm = colM[n];
                    int cc = colC[n];
                    cs += __shfl_xor(cs, 16); cs += __shfl_xor(cs, 32);
                    cc += __shfl_xor(cc, 16); cc += __shfl_xor(cc, 32);
                    cm = fmaxf(cm, __shfl_xor(cm, 16));
                    cm = fmaxf(cm, __shfl_xor(cm, 32));
                    if (kgrp == 0) {
                        int gcol = C0 + n * 16 + lrow;
                        sum_part[(size_t)gcol * 64 + rt] = cs;
                        cnt_part[(size_t)gcol * 64 + rt] = cc;
                        max_part[(size_t)gcol * 64 + rt] = cm;
                    }
                }
            }

            #pragma unroll
            for (int off = 1; off < 64; off <<= 1) allmax = fmaxf(allmax, __shfl_xor(allmax, off));
            if (l == 0) atomicMax(gmax, fkey(allmax));
        }
    }

    // ---- block barrier on all tiles done ----
    __syncthreads();
    __threadfence();   // release partials
    if (t == 0)
        __hip_atomic_fetch_add(sem2, 1u, __ATOMIC_RELAXED, __HIP_MEMORY_SCOPE_AGENT);
    if (t == 0) {
        while (__hip_atomic_load(sem2, __ATOMIC_RELAXED, __HIP_MEMORY_SCOPE_AGENT) < (unsigned)NBLK)
            __builtin_amdgcn_s_sleep(8);
    }
    __syncthreads();
    __threadfence();   // acquire: see all partials + gmax

    // ===================== PHASE 3: rows bid*8..bid*8+7 =====================
    {
        float base = fmaxf(fdec(*gmax) - 0.1f, MARGIN + 0.2f);
        #pragma unroll
        for (int rr = 0; rr < 2; ++rr) {
            int row = bid * 8 + w * 2 + rr;
            float ns = sum_part[(size_t)row * 64 + l];
            int nc = cnt_part[(size_t)row * 64 + l];
            float nm = max_part[(size_t)row * 64 + l];
            #pragma unroll
            for (int off = 1; off < 64; off <<= 1) {
                ns += __shfl_xor(ns, off);
                nc += __shfl_xor(nc, off);
                nm = fmaxf(nm, __shfl_xor(nm, off));
            }
            if (l == 0) {
                float neg_loss = (nc > 0) ? ns / (float)nc : softplus(ALPHA * (nm - MARGIN));
                float ps = 0.f;
                int pcnt = 0;
                float mn = min_pos[row];
                #pragma unroll
                for (int i = 0; i < NINST - 1; ++i) {
                    float s = pos_sims[(size_t)row * 8 + i];
                    if (s < base) { ps += softplus(-2.0f * (s - MARGIN)); pcnt++; }
                }
                float pos_loss = (pcnt > 0) ? ps / (float)pcnt : softplus(-2.0f * (mn - MARGIN));
                sloss[w * 2 + rr] = pos_loss + neg_loss;
            }
        }
        __syncthreads();
        if (t == 0) {
            float bs = 0.f;
            #pragma unroll
            for (int i = 0; i < 8; ++i) bs += sloss[i];
            atomicAdd(&accum[bid & 31], bs);
            __threadfence();
            unsigned old = atomicAdd(cnt3, 1u);
            if (old == (unsigned)(NBLK - 1)) {
                __threadfence();
                float tot = 0.f;
                for (int j = 0; j < 32; ++j) tot += atomicAdd(&accum[j], 0.0f);
                out[0] = tot / (float)N;
            }
        }
    }
}

extern "C" void kernel_launch(void* const* d_in, const int* in_sizes, int n_in,
                              void* d_out, int out_size, void* d_ws, size_t ws_size,
                              hipStream_t stream) {
    const float* in = (const float*)d_in[0];
    float* out = (float*)d_out;

    char* ws = (char*)d_ws;
    unsigned long* xn8 = (unsigned long*)(ws);                  // 4 MB (banded fragment-major)
    float*   min_pos  = (float*)(ws + 8388608 + 16384);         // 16 KB
    float*   pos_sims = (float*)(ws + 8388608 + 32768);         // 128 KB
    float*   sum_part = (float*)(ws + 8388608 + 32768 + 131072);            // 1 MB
    float*   max_part = (float*)(ws + 8388608 + 32768 + 131072 + 1048576);  // 1 MB
    int*     cnt_part = (int*)  (ws + 8388608 + 32768 + 131072 + 2097152);  // 1 MB
    unsigned* ctrl    = (unsigned*)(ws + 8388608 + 32768 + 131072 + 3145728);      // 68 u32
    float*   accum    = (float*)(ws + 8388608 + 32768 + 131072 + 3145728 + 384);   // 32 f32

    // zero gmax/sem2/cnt3/band_cnt/accum each launch (capture-safe)
    hipMemsetAsync(ctrl, 0, 512, stream);

    k_all<<<NBLK, 256, 0, stream>>>(in, xn8, pos_sims, min_pos,
                                    sum_part, cnt_part, max_part,
                                    ctrl, accum, out);
}

// Round 19
// 101.201 us; speedup vs baseline: 3.1229x; 3.1229x over previous
//
#include <hip/hip_runtime.h>
#include <hip/hip_bf16.h>
#include <hip/hip_fp8.h>
#include <math.h>

#define N 4096
#define D 1024
#define NINST 8
#define NGROUP (N / NINST)
#define ALPHA 20.0f
#define MARGIN 0.5f
#define NB2 32                        // 32 bands of 128 rows
#define NTILE2 (NB2 * (NB2 + 1) / 2)  // 528 triangular 128x128 tiles

typedef __attribute__((ext_vector_type(4))) float f32x4;

__device__ __forceinline__ unsigned fkey(float f) {
    int b = __float_as_int(f);
    return (b >= 0) ? ((unsigned)b | 0x80000000u) : ~(unsigned)b;
}
__device__ __forceinline__ float fdec(unsigned u) {
    int b = (u & 0x80000000u) ? (int)(u ^ 0x80000000u) : ~(int)u;
    return __int_as_float(b);
}

// stable fast softplus: log1p(exp(x)) = max(x,0) + log(1 + exp(-|x|))
__device__ __forceinline__ float softplus(float x) {
    float z = __expf(-fabsf(x));
    return fmaxf(x, 0.0f) + __logf(1.0f + z);
}

// async global -> LDS, 16 bytes per lane (lds dest: wave-uniform base + lane*16)
__device__ __forceinline__ void gld16(const void* g, void* l) {
    __builtin_amdgcn_global_load_lds(
        (const __attribute__((address_space(1))) void*)g,
        (__attribute__((address_space(3))) void*)l, 16, 0, 0);
}

// ---------------- K1: per-group normalize + banded fragment-major fp8 write + fp32 Gram ----
// (R17 512-thread version, unchanged.) xn8 layout (ulong units): idx = band64*8192 +
// kstep*256 + m*64 + slot; band64 = row>>6, m = (row>>4)&3, slot = oct*16 + (row&15).
__global__ __launch_bounds__(512) void k_normpos(const float* __restrict__ in,
                                                 unsigned long* __restrict__ xn8,
                                                 float* __restrict__ pos_sims,
                                                 float* __restrict__ min_pos,
                                                 unsigned* __restrict__ gmax,
                                                 float* __restrict__ accum,
                                                 unsigned* __restrict__ cnt) {
    __shared__ float4 srows4[8 * 257];
    __shared__ float spart[8][4];
    __shared__ float sinv[8];
    __shared__ float sg[8][8];

    int g = blockIdx.x;
    int t = threadIdx.x;
    int lane = t & 63;
    int w = t >> 6;
    int par = t >> 8;

    if (g == 0) {
        if (t == 0) { *gmax = 0u; *cnt = 0u; }
        if (t < 32) accum[t] = 0.f;
    }

    const float4* in4 = (const float4*)in;
    #pragma unroll
    for (int k = 0; k < 4; ++k) {
        float4 v = in4[(size_t)g * 2048 + k * 512 + t];
        int row = 2 * k + par;
        srows4[row * 257 + (t & 255)] = v;
        float ss = v.x * v.x + v.y * v.y + v.z * v.z + v.w * v.w;
        #pragma unroll
        for (int off = 1; off < 64; off <<= 1) ss += __shfl_xor(ss, off);
        if (lane == 0) spart[row][w & 3] = ss;
    }
    __syncthreads();
    if (t < 8) sinv[t] = rsqrtf(spart[t][0] + spart[t][1] + spart[t][2] + spart[t][3]);
    __syncthreads();

    {
        int i_row = t & 7;
        int oct  = (t >> 3) & 3;
        int k0b  = (t >> 5) & 7;
        int hi   = t >> 8;
        size_t base = (size_t)(g >> 3) * 8192 + (size_t)((g >> 1) & 3) * 64
                    + (size_t)(oct * 16 + (g & 1) * 8 + i_row);
        float inv = sinv[i_row];
        #pragma unroll
        for (int jj = 0; jj < 2; ++jj) {
            int k0 = k0b + (hi * 2 + jj) * 8;
            float4 v0 = srows4[i_row * 257 + k0 * 8 + oct * 2];
            float4 v1 = srows4[i_row * 257 + k0 * 8 + oct * 2 + 1];
            union { unsigned char c[8]; unsigned long u64; } o;
            o.c[0] = __hip_fp8_e4m3(v0.x * inv).__x;
            o.c[1] = __hip_fp8_e4m3(v0.y * inv).__x;
            o.c[2] = __hip_fp8_e4m3(v0.z * inv).__x;
            o.c[3] = __hip_fp8_e4m3(v0.w * inv).__x;
            o.c[4] = __hip_fp8_e4m3(v1.x * inv).__x;
            o.c[5] = __hip_fp8_e4m3(v1.y * inv).__x;
            o.c[6] = __hip_fp8_e4m3(v1.z * inv).__x;
            o.c[7] = __hip_fp8_e4m3(v1.w * inv).__x;
            xn8[base + (size_t)k0 * 256] = o.u64;
        }
    }

    int pair = t >> 3, a = pair >> 3, b = pair & 7, slice = t & 7;
    const float4* pa = srows4 + a * 257 + slice * 32;
    const float4* pb = srows4 + b * 257 + slice * 32;
    int j0 = ((pair << 1) + slice) & 31;
    float s = 0.f;
    #pragma unroll 8
    for (int i = 0; i < 32; ++i) {
        int j = (i + j0) & 31;
        float4 x = pa[j], y = pb[j];
        s += x.x * y.x + x.y * y.y + x.z * y.z + x.w * y.w;
    }
    s += __shfl_xor(s, 1);
    s += __shfl_xor(s, 2);
    s += __shfl_xor(s, 4);
    if (slice == 0) sg[a][b] = s * sinv[a] * sinv[b];
    __syncthreads();
    if (t < 8) {
        float mn = 1e30f;
        int idx = 0;
        #pragma unroll
        for (int b2 = 0; b2 < 8; ++b2) {
            if (b2 == t) continue;
            float v = sg[t][b2];
            mn = fminf(mn, v);
            pos_sims[(size_t)(g * 8 + t) * 8 + idx] = v;
            ++idx;
        }
        min_pos[g * 8 + t] = mn;
    }
}

// ---------------- K2: fp8 MFMA sim tiles, 128x128, 4 waves (2x2), 2-phase dbuf ----------
// grid 528 triangular tiles over 32 bands of 128; block 256 thr. Per k-step (32 fp8):
// stage 8KB (2 gld16/wave, contiguous 1KB each) into dbuf; prefetch-next -> ds_read
// -> 16 MFMA/wave -> __syncthreads (drains prefetch under MFMA). Staging halves vs
// 64^2 tiles: 135 MB total. Epilogue = proven R6 slot map (row + transpose col stats).
__global__ __launch_bounds__(256, 4) void k_neg(const unsigned long* __restrict__ xn8,
                                                const float* __restrict__ min_pos,
                                                float* __restrict__ sum_part,
                                                int* __restrict__ cnt_part,
                                                float* __restrict__ max_part,
                                                unsigned* __restrict__ gmax) {
    __shared__ char sbuf[2][8192];   // [buf][A 4KB | B 4KB] = 16 KB
    __shared__ float sMinA[128];
    __shared__ float sMinB[128];

    // decode triangular tile index (rt, ct), ct >= rt, over 32 bands
    int bid = blockIdx.x;
    int rt = 0, rem = bid;
    while (rem >= NB2 - rt) { rem -= NB2 - rt; ++rt; }
    int ct = rt + rem;
    bool diag = (rt == ct);

    int R0 = rt * 128, C0 = ct * 128;
    int t = threadIdx.x, l = t & 63, w = t >> 6;
    int wr = w >> 1, wc = w & 1;
    int lrow = l & 15;
    int kgrp = l >> 4;

    if (t < 128) { sMinA[t] = min_pos[R0 + t]; sMinB[t] = min_pos[C0 + t]; }

    // staging: wave w covers {A|B} x {lower|upper 64-band}: 2 gld16/step
    int half = w & 1;
    int isB = w >> 1;
    int pbase = diag ? R0 : (isB ? C0 : R0);
    const char* gsrc = (const char*)xn8 + (size_t)((pbase >> 6) + half) * 65536 + (size_t)l * 16;
    // LDS dest: A at [0,4K) = band panels {0,1}x2KB; B at [4K,8K)
    unsigned ldso = (unsigned)(isB * 4096 + half * 2048);

    #define STAGE(buf, s_)                                              \
        do {                                                            \
            char* d_ = sbuf[buf] + ldso;                                \
            gld16(gsrc + (size_t)(s_) * 2048,        d_);               \
            gld16(gsrc + (size_t)(s_) * 2048 + 1024, d_ + 1024);        \
        } while (0)

    f32x4 zero = {0.f, 0.f, 0.f, 0.f};
    f32x4 acc[4][4];
    #pragma unroll
    for (int m = 0; m < 4; ++m)
        #pragma unroll
        for (int n = 0; n < 4; ++n) acc[m][n] = zero;

    STAGE(0, 0);
    __syncthreads();

    for (int it = 0; it < 32; ++it) {
        if (it + 1 < 32) STAGE((it & 1) ^ 1, it + 1);   // prefetch next step

        const char* bufp = sbuf[it & 1];
        const char* fA = bufp + wr * 2048 + l * 8;
        const char* fB = bufp + 4096 + wc * 2048 + l * 8;
        long a[4], b[4];
        #pragma unroll
        for (int m = 0; m < 4; ++m) {
            a[m] = *(const long*)(fA + m * 512);
            b[m] = *(const long*)(fB + m * 512);
        }
        #pragma unroll
        for (int m = 0; m < 4; ++m)
            #pragma unroll
            for (int n = 0; n < 4; ++n)
                acc[m][n] = __builtin_amdgcn_mfma_f32_16x16x32_fp8_fp8(
                    a[m], b[n], acc[m][n], 0, 0, 0);

        __syncthreads();   // drains prefetch (flew under MFMAs) + guards reuse
    }
    #undef STAGE

    // ---- epilogue (R6-proven): row-band stats; col-band (transpose) stats off-diag ----
    float allmax = -1e30f;
    int cbase = C0 + wc * 64;
    int pcRow = ct * 2 + wc;     // row-stat slot
    int pcCol = rt * 2 + wr;     // col-stat slot (transpose contribution)

    float thB[4];
    #pragma unroll
    for (int n = 0; n < 4; ++n) thB[n] = sMinB[wc * 64 + n * 16 + lrow] - 0.05f;

    float colS[4] = {0.f, 0.f, 0.f, 0.f};
    float colM[4] = {-1e30f, -1e30f, -1e30f, -1e30f};
    int   colC[4] = {0, 0, 0, 0};

    #pragma unroll
    for (int m = 0; m < 4; ++m) {
        #pragma unroll
        for (int reg = 0; reg < 4; ++reg) {
            int lr = wr * 64 + m * 16 + kgrp * 4 + reg;   // local row in [0,128)
            int grow = R0 + lr;
            float th = sMinA[lr] - 0.05f;
            int gi = grow >> 3;
            float rs = 0.f, rm = -1e30f;
            int rc = 0;
            #pragma unroll
            for (int n = 0; n < 4; ++n) {
                int gcol = cbase + n * 16 + lrow;
                float s = acc[m][n][reg];
                allmax = fmaxf(allmax, s);
                if ((gcol >> 3) != gi) {
                    float e = softplus(ALPHA * (s - MARGIN));
                    rm = fmaxf(rm, s);
                    if (s > th) { rs += e; rc += 1; }
                    if (!diag) {
                        colM[n] = fmaxf(colM[n], s);
                        if (s > thB[n]) { colS[n] += e; colC[n] += 1; }
                    }
                }
            }
            #pragma unroll
            for (int off = 1; off < 16; off <<= 1) {
                rs += __shfl_xor(rs, off);
                rc += __shfl_xor(rc, off);
                rm = fmaxf(rm, __shfl_xor(rm, off));
            }
            if (lrow == 0) {
                sum_part[(size_t)grow * 64 + pcRow] = rs;
                cnt_part[(size_t)grow * 64 + pcRow] = rc;
                max_part[(size_t)grow * 64 + pcRow] = rm;
            }
        }
    }

    if (!diag) {
        #pragma unroll
        for (int n = 0; n < 4; ++n) {
            float cs = colS[n], cm = colM[n];
            int cc = colC[n];
            cs += __shfl_xor(cs, 16); cs += __shfl_xor(cs, 32);
            cc += __shfl_xor(cc, 16); cc += __shfl_xor(cc, 32);
            cm = fmaxf(cm, __shfl_xor(cm, 16));
            cm = fmaxf(cm, __shfl_xor(cm, 32));
            if (kgrp == 0) {
                int gcol = cbase + n * 16 + lrow;
                sum_part[(size_t)gcol * 64 + pcCol] = cs;
                cnt_part[(size_t)gcol * 64 + pcCol] = cc;
                max_part[(size_t)gcol * 64 + pcCol] = cm;
            }
        }
    }

    #pragma unroll
    for (int off = 1; off < 64; off <<= 1) allmax = fmaxf(allmax, __shfl_xor(allmax, off));
    if (l == 0) atomicMax(gmax, fkey(allmax));
}

// ---------------- K3: per-row combine (64 slots/row) + spread-atomic final mean ----------------
__global__ __launch_bounds__(256) void k_rowfinal(const float* __restrict__ sum_part,
                                                  const int* __restrict__ cnt_part,
                                                  const float* __restrict__ max_part,
                                                  const float* __restrict__ pos_sims,
                                                  const float* __restrict__ min_pos,
                                                  const unsigned* __restrict__ gmax,
                                                  float* __restrict__ accum,
                                                  unsigned* __restrict__ cnt,
                                                  float* __restrict__ out) {
    __shared__ float sloss[4];
    int row = blockIdx.x * 4 + (threadIdx.x >> 6);
    int lane = threadIdx.x & 63;
    float ns = sum_part[(size_t)row * 64 + lane];
    int nc = cnt_part[(size_t)row * 64 + lane];
    float nm = max_part[(size_t)row * 64 + lane];
    #pragma unroll
    for (int off = 1; off < 64; off <<= 1) {
        ns += __shfl_xor(ns, off);
        nc += __shfl_xor(nc, off);
        nm = fmaxf(nm, __shfl_xor(nm, off));
    }
    if (lane == 0) {
        float base = fmaxf(fdec(*gmax) - 0.1f, MARGIN + 0.2f);
        float neg_loss = (nc > 0) ? ns / (float)nc : softplus(ALPHA * (nm - MARGIN));
        float ps = 0.f;
        int pcnt = 0;
        float mn = min_pos[row];
        #pragma unroll
        for (int i = 0; i < NINST - 1; ++i) {
            float s = pos_sims[(size_t)row * 8 + i];
            if (s < base) { ps += softplus(-2.0f * (s - MARGIN)); pcnt++; }
        }
        float pos_loss = (pcnt > 0) ? ps / (float)pcnt : softplus(-2.0f * (mn - MARGIN));
        sloss[threadIdx.x >> 6] = pos_loss + neg_loss;
    }
    __syncthreads();
    if (threadIdx.x == 0) {
        float bs = sloss[0] + sloss[1] + sloss[2] + sloss[3];
        atomicAdd(&accum[blockIdx.x & 31], bs);
        __threadfence();
        unsigned old = atomicAdd(cnt, 1u);
        if (old == gridDim.x - 1) {
            __threadfence();
            float tot = 0.f;
            for (int j = 0; j < 32; ++j) tot += atomicAdd(&accum[j], 0.0f);
            out[0] = tot / (float)N;
        }
    }
}

extern "C" void kernel_launch(void* const* d_in, const int* in_sizes, int n_in,
                              void* d_out, int out_size, void* d_ws, size_t ws_size,
                              hipStream_t stream) {
    const float* in = (const float*)d_in[0];
    float* out = (float*)d_out;

    char* ws = (char*)d_ws;
    unsigned long* xn8 = (unsigned long*)(ws);                  // 4 MB (banded fragment-major)
    float*   min_pos  = (float*)(ws + 8388608 + 16384);         // 16 KB
    float*   pos_sims = (float*)(ws + 8388608 + 32768);         // 128 KB
    float*   sum_part = (float*)(ws + 8388608 + 32768 + 131072);            // 1 MB
    float*   max_part = (float*)(ws + 8388608 + 32768 + 131072 + 1048576);  // 1 MB
    int*     cnt_part = (int*)  (ws + 8388608 + 32768 + 131072 + 2097152);  // 1 MB
    unsigned* gmax    = (unsigned*)(ws + 8388608 + 32768 + 131072 + 3145728);
    float*   accum    = (float*)(ws + 8388608 + 32768 + 131072 + 3145728 + 128);  // 32 floats
    unsigned* cnt     = (unsigned*)(ws + 8388608 + 32768 + 131072 + 3145728 + 256);

    k_normpos<<<NGROUP, 512, 0, stream>>>(in, xn8, pos_sims, min_pos, gmax, accum, cnt);
    k_neg<<<NTILE2, 256, 0, stream>>>(xn8, min_pos, sum_part, cnt_part, max_part, gmax);
    k_rowfinal<<<N / 4, 256, 0, stream>>>(sum_part, cnt_part, max_part, pos_sims, min_pos,
                                          gmax, accum, cnt, out);
}